// Round 9
// baseline (143.020 us; speedup 1.0000x reference)
//
#include <hip/hip_runtime.h>
#include <hip/hip_bf16.h>

#define NRES 256
#define DPAIR 128
#define NHEADS 16
#define DHEAD 32
#define DINNER 512

typedef unsigned short u16;
typedef __attribute__((ext_vector_type(4))) float f32x4;
typedef __attribute__((ext_vector_type(8))) short s16x8;
typedef __attribute__((ext_vector_type(4))) short s16x4;

// (1/sqrt(32)) * log2(e): folded into q so softmax can use exp2 directly.
#define QSCALE (0.17677669529663687f * 1.4426950408889634f)

__device__ __forceinline__ u16 f32_to_bf16(float f) {
    unsigned int u = __builtin_bit_cast(unsigned int, f);
    unsigned int r = (u + 0x7FFFu + ((u >> 16) & 1u)) >> 16;
    return (u16)r;
}

__device__ __forceinline__ float fast_exp2(float x) {
#if __has_builtin(__builtin_amdgcn_exp2f)
    return __builtin_amdgcn_exp2f(x);
#else
    return exp2f(x);
#endif
}

__device__ __forceinline__ f32x4 mfma_16x16x16_bf16(s16x4 a, s16x4 b, f32x4 c) {
#if __has_builtin(__builtin_amdgcn_mfma_f32_16x16x16bf16_1k)
    return __builtin_amdgcn_mfma_f32_16x16x16bf16_1k(a, b, c, 0, 0, 0);
#elif __has_builtin(__builtin_amdgcn_mfma_f32_16x16x16_bf16)
    return __builtin_amdgcn_mfma_f32_16x16x16_bf16(a, b, c, 0, 0, 0);
#else
    f32x4 d;
    asm volatile("v_mfma_f32_16x16x16_bf16 %0, %1, %2, %3"
                 : "=v"(d) : "v"(a), "v"(b), "v"(c));
    return d;
#endif
}

// async global->LDS, 16B per lane. LDS dest is wave-uniform base + lane*16.
__device__ __forceinline__ void gll16(const void* g, void* l) {
    __builtin_amdgcn_global_load_lds(
        (__attribute__((address_space(1))) unsigned int*)(uintptr_t)g,
        (__attribute__((address_space(3))) unsigned int*)(unsigned int)(uintptr_t)l,
        16, 0, 0);
}

// ---------------- prep: weight convert/transpose + pair f32->bf16 (merged) ----------------
__global__ __launch_bounds__(256) void prep_all(const float* __restrict__ Wq,
                                                const float* __restrict__ Wk,
                                                const float* __restrict__ Wv,
                                                const float* __restrict__ Wo,
                                                const float* __restrict__ pair,
                                                u16* wq_t, u16* wk_t, u16* wv_t, u16* wo_t,
                                                u16* __restrict__ pairb) {
    const int b = blockIdx.x;
    if (b < 1024) {
        int id = b * 256 + threadIdx.x;
        if (id < 3 * 65536) {
            int m = id / 65536;
            int e = id % 65536;
            int k = e >> 9, n = e & 511;
            const float* W = (m == 0) ? Wq : ((m == 1) ? Wk : Wv);
            u16* Wt = (m == 0) ? wq_t : ((m == 1) ? wk_t : wv_t);
            Wt[n * 128 + k] = f32_to_bf16(W[e]);
        } else {
            int e = id - 3 * 65536;
            int k = e >> 7, n = e & 127;
            wo_t[n * 512 + k] = f32_to_bf16(Wo[e]);
        }
    } else {
        const int id = (b - 1024) * 256 + threadIdx.x;   // 1048576 ids x 8 elems
        const float4* s = reinterpret_cast<const float4*>(pair) + (size_t)id * 2;
        const float4 v0 = s[0], v1 = s[1];
        ushort4 lo, hi;
        lo.x = f32_to_bf16(v0.x); lo.y = f32_to_bf16(v0.y);
        lo.z = f32_to_bf16(v0.z); lo.w = f32_to_bf16(v0.w);
        hi.x = f32_to_bf16(v1.x); hi.y = f32_to_bf16(v1.y);
        hi.z = f32_to_bf16(v1.z); hi.w = f32_to_bf16(v1.w);
        ushort4* d = reinterpret_cast<ushort4*>(pairb + (size_t)id * 8);
        d[0] = lo; d[1] = hi;
    }
}

// ---------------- Fused QKV-projection + triangular attention per (i,h) ----------------
// 512 threads = 8 waves. Pair rows in registers. LDS PHASE-OVERLAY:
//   phase 0/1: wS (24576B) at offset 0 — weight slices, read by QKV MFMA loop.
//   [barrier]  wS dead.
//   phase 2/3: qS (16384B) at 0, vTS (16896B) at 16384, kS (20480B) at 33280.
// Total 53760B -> 3 blocks/CU (6 waves/SIMD), up from 2.
__global__ __launch_bounds__(512, 6) void fused_attn(const u16* __restrict__ pairb,
                                                     const u16* __restrict__ wq_t,
                                                     const u16* __restrict__ wk_t,
                                                     const u16* __restrict__ wv_t,
                                                     const float* __restrict__ bq,
                                                     const float* __restrict__ bk,
                                                     const float* __restrict__ bv,
                                                     u16* __restrict__ o_ws) {
    __shared__ __align__(128) char ldsbuf[53760];
    u16* const wS  = (u16*)ldsbuf;               // [m][c][k] linear, source-XOR by (c&7)
    u16* const qS  = (u16*)ldsbuf;               // [j][c], 16B-chunk XOR-swizzled by (j&3)
    u16* const vTS = (u16*)(ldsbuf + 16384);     // [c][j] pitch 264
    u16* const kS  = (u16*)(ldsbuf + 33280);     // [j][c] pitch 40

    // XCD swizzle: the 16 h-blocks of one i stay on one XCD (pair rows L2-shared).
    const int bx = ((blockIdx.x & 7) << 9) | (blockIdx.x >> 3);
    const int i = bx >> 4, h = bx & 15;
    const int tid = threadIdx.x;
    const int wave = tid >> 6, lane = tid & 63;   // wave 0..7
    const int g = lane >> 4, l15 = lane & 15;
    const int j0 = wave * 32;

    // ---- stage W slices: 3 x 8KiB = 24 chunks, 3 per wave (async to LDS) ----
    for (int it = 0; it < 3; ++it) {
        const int chunk = wave * 3 + it;          // 0..23
        const int m = chunk >> 3;
        const int lc = chunk & 7;
        const u16* Wt = (m == 0) ? wq_t : ((m == 1) ? wk_t : wv_t);
        const int c = lc * 4 + (lane >> 4);       // 0..31 within slice
        const int col = (lane & 15) ^ (c & 7);
        gll16((const char*)(Wt + (size_t)(h * 32) * 128) + c * 256 + col * 16,
              (void*)(wS + (m * 32 + lc * 4) * 128));
    }
    // ---- pair rows straight to registers (wave-private!) ----
    s16x8 pf[2][4];
    {
        const u16* prow = pairb + (size_t)(i * 256 + j0 + l15) * 128;
        #pragma unroll
        for (int jf = 0; jf < 2; ++jf)
            #pragma unroll
            for (int kk = 0; kk < 4; ++kk)
                pf[jf][kk] = *reinterpret_cast<const s16x8*>(prow + jf * 16 * 128 + kk * 32 + g * 8);
    }
    __syncthreads();   // drains gll16 (vmcnt) + barrier

    // ---- QKV mini-GEMM: wave owns 32 j-rows x all 32 cols, K=128 ----
    f32x4 aq[2][2], ak[2][2], av[2][2];   // q/k: [cf][jf] (swapped); v: [jf][cf]
    {
        #pragma unroll
        for (int a = 0; a < 2; ++a)
            #pragma unroll
            for (int b = 0; b < 2; ++b) {
                aq[a][b] = f32x4{0.f, 0.f, 0.f, 0.f};
                ak[a][b] = f32x4{0.f, 0.f, 0.f, 0.f};
                av[a][b] = f32x4{0.f, 0.f, 0.f, 0.f};
            }
        #pragma unroll
        for (int kk = 0; kk < 4; ++kk) {
            s16x8 wf[3][2];
            #pragma unroll
            for (int m = 0; m < 3; ++m)
                #pragma unroll
                for (int cf = 0; cf < 2; ++cf) {
                    const int c = cf * 16 + l15;
                    const int ch = (kk * 4 + g) ^ (c & 7);
                    wf[m][cf] = *reinterpret_cast<s16x8*>(&wS[(m * 32 + c) * 128 + ch * 8]);
                }
            #pragma unroll
            for (int cf = 0; cf < 2; ++cf)
                #pragma unroll
                for (int jf = 0; jf < 2; ++jf) {
                    aq[cf][jf] = __builtin_amdgcn_mfma_f32_16x16x32_bf16(wf[0][cf], pf[jf][kk], aq[cf][jf], 0, 0, 0);
                    ak[cf][jf] = __builtin_amdgcn_mfma_f32_16x16x32_bf16(wf[1][cf], pf[jf][kk], ak[cf][jf], 0, 0, 0);
                    av[jf][cf] = __builtin_amdgcn_mfma_f32_16x16x32_bf16(pf[jf][kk], wf[2][cf], av[jf][cf], 0, 0, 0);
                }
        }
    }
    __syncthreads();   // wS fully read by ALL waves; qS/vTS may now overwrite it

    // ---- epilogue: write q/k/vT into (overlaid) LDS ----
    {
        // q/k lane holds [j=j0+jf*16+l15][c=cf*16+g*4+(0..3)]
        #pragma unroll
        for (int cf = 0; cf < 2; ++cf) {
            const int c = cf * 16 + g * 4;
            const float4 b4q = *reinterpret_cast<const float4*>(bq + h * 32 + c);
            const float4 b4k = *reinterpret_cast<const float4*>(bk + h * 32 + c);
            #pragma unroll
            for (int jf = 0; jf < 2; ++jf) {
                const int j = j0 + jf * 16 + l15;
                ushort4 oq, ok;
                oq.x = f32_to_bf16((aq[cf][jf][0] + b4q.x) * QSCALE);
                oq.y = f32_to_bf16((aq[cf][jf][1] + b4q.y) * QSCALE);
                oq.z = f32_to_bf16((aq[cf][jf][2] + b4q.z) * QSCALE);
                oq.w = f32_to_bf16((aq[cf][jf][3] + b4q.w) * QSCALE);
                // 16B-chunk XOR swizzle: chunk cc = 2cf + (g>>1), pos = cc ^ (j&3)
                *reinterpret_cast<ushort4*>(
                    &qS[j * 32 + (((cf << 1) + (g >> 1)) ^ (j & 3)) * 8 + (g & 1) * 4]) = oq;
                ok.x = f32_to_bf16(ak[cf][jf][0] + b4k.x);
                ok.y = f32_to_bf16(ak[cf][jf][1] + b4k.y);
                ok.z = f32_to_bf16(ak[cf][jf][2] + b4k.z);
                ok.w = f32_to_bf16(ak[cf][jf][3] + b4k.w);
                *reinterpret_cast<ushort4*>(&kS[j * 40 + c]) = ok;
            }
        }
        // v: lane holds [j=j0+jf*16+g*4+(0..3)][c=cf*16+l15] -> vTS[c][j]
        #pragma unroll
        for (int cf = 0; cf < 2; ++cf) {
            const int c = cf * 16 + l15;
            const float bvv = bv[h * 32 + c];
            #pragma unroll
            for (int jf = 0; jf < 2; ++jf) {
                const int j = j0 + jf * 16 + g * 4;
                ushort4 ov;
                ov.x = f32_to_bf16(av[jf][cf][0] + bvv);
                ov.y = f32_to_bf16(av[jf][cf][1] + bvv);
                ov.z = f32_to_bf16(av[jf][cf][2] + bvv);
                ov.w = f32_to_bf16(av[jf][cf][3] + bvv);
                *reinterpret_cast<ushort4*>(&vTS[c * 264 + j]) = ov;
            }
        }
    }
    __syncthreads();

    // ---- attention: chunks tA=wave, tB=15-wave interleaved (tA < tB always) ----
    const size_t obase = ((size_t)i * 256) * 512 + h * 32;
    const int tA = wave, tB = 15 - wave;

    const s16x8 qfA = *reinterpret_cast<const s16x8*>(
        &qS[(tA * 16 + l15) * 32 + (g ^ (l15 & 3)) * 8]);
    const s16x8 qfB = *reinterpret_cast<const s16x8*>(
        &qS[(tB * 16 + l15) * 32 + (g ^ (l15 & 3)) * 8]);

    f32x4 accA0 = {0.f, 0.f, 0.f, 0.f}, accA1 = {0.f, 0.f, 0.f, 0.f};
    f32x4 accB0 = {0.f, 0.f, 0.f, 0.f}, accB1 = {0.f, 0.f, 0.f, 0.f};
    float sumA = 0.f, sumB = 0.f;

    auto rdK = [&](int kt) {
        return *reinterpret_cast<s16x8*>(&kS[(kt * 16 + l15) * 40 + g * 8]);
    };
    auto rdV0 = [&](int kt) {
        return *reinterpret_cast<s16x4*>(&vTS[l15 * 264 + kt * 16 + g * 4]);
    };
    auto rdV1 = [&](int kt) {
        return *reinterpret_cast<s16x4*>(&vTS[(16 + l15) * 264 + kt * 16 + g * 4]);
    };
    auto tile = [&](const s16x8& kf, const s16x4& va0, const s16x4& va1,
                    const s16x8& qf, f32x4& a0, f32x4& a1, float& sm, bool dg) {
        f32x4 s = __builtin_amdgcn_mfma_f32_16x16x32_bf16(kf, qf, f32x4{0.f, 0.f, 0.f, 0.f}, 0, 0, 0);
        // s[r] = S[k = kt*16 + g*4 + r][j] (log2 domain)
        float p0, p1, p2, p3;
        if (dg) {  // diagonal tile: mask k > j
            p0 = ((g * 4 + 0) > l15) ? 0.f : fast_exp2(s[0]);
            p1 = ((g * 4 + 1) > l15) ? 0.f : fast_exp2(s[1]);
            p2 = ((g * 4 + 2) > l15) ? 0.f : fast_exp2(s[2]);
            p3 = ((g * 4 + 3) > l15) ? 0.f : fast_exp2(s[3]);
        } else {
            p0 = fast_exp2(s[0]); p1 = fast_exp2(s[1]);
            p2 = fast_exp2(s[2]); p3 = fast_exp2(s[3]);
        }
        sm += (p0 + p1) + (p2 + p3);
        unsigned e0 = __builtin_bit_cast(unsigned, p0) + 0x8000u;
        unsigned e1 = __builtin_bit_cast(unsigned, p1) + 0x8000u;
        unsigned e2 = __builtin_bit_cast(unsigned, p2) + 0x8000u;
        unsigned e3 = __builtin_bit_cast(unsigned, p3) + 0x8000u;
        uint2 pw;
        pw.x = __builtin_amdgcn_perm(e1, e0, 0x07060302u);
        pw.y = __builtin_amdgcn_perm(e3, e2, 0x07060302u);
        const s16x4 pb = __builtin_bit_cast(s16x4, pw);
        a0 = mfma_16x16x16_bf16(va0, pb, a0);
        a1 = mfma_16x16x16_bf16(va1, pb, a1);
    };

    for (int kt = 0; kt < tA; ++kt) {
        const s16x8 kf = rdK(kt);
        const s16x4 v0 = rdV0(kt), v1 = rdV1(kt);
        tile(kf, v0, v1, qfB, accB0, accB1, sumB, false);
        tile(kf, v0, v1, qfA, accA0, accA1, sumA, false);
    }
    {   // kt == tA: A's diagonal; B regular (tA < tB)
        const s16x8 kf = rdK(tA);
        const s16x4 v0 = rdV0(tA), v1 = rdV1(tA);
        tile(kf, v0, v1, qfB, accB0, accB1, sumB, false);
        tile(kf, v0, v1, qfA, accA0, accA1, sumA, true);
    }
    for (int kt = tA + 1; kt < tB; ++kt) {
        const s16x8 kf = rdK(kt);
        const s16x4 v0 = rdV0(kt), v1 = rdV1(kt);
        tile(kf, v0, v1, qfB, accB0, accB1, sumB, false);
    }
    {   // kt == tB: B's diagonal
        const s16x8 kf = rdK(tB);
        const s16x4 v0 = rdV0(tB), v1 = rdV1(tB);
        tile(kf, v0, v1, qfB, accB0, accB1, sumB, true);
    }

    auto store_o = [&](int jbase, const f32x4& o0, const f32x4& o1, float sum) {
        sum += __shfl_xor(sum, 16, 64);
        sum += __shfl_xor(sum, 32, 64);
        const float rinv = 1.0f / sum;
        unsigned x0 = __builtin_bit_cast(unsigned, o0[0] * rinv) + 0x8000u;
        unsigned x1 = __builtin_bit_cast(unsigned, o0[1] * rinv) + 0x8000u;
        unsigned x2 = __builtin_bit_cast(unsigned, o0[2] * rinv) + 0x8000u;
        unsigned x3 = __builtin_bit_cast(unsigned, o0[3] * rinv) + 0x8000u;
        uint2 w0;
        w0.x = __builtin_amdgcn_perm(x1, x0, 0x07060302u);
        w0.y = __builtin_amdgcn_perm(x3, x2, 0x07060302u);
        unsigned y0 = __builtin_bit_cast(unsigned, o1[0] * rinv) + 0x8000u;
        unsigned y1 = __builtin_bit_cast(unsigned, o1[1] * rinv) + 0x8000u;
        unsigned y2 = __builtin_bit_cast(unsigned, o1[2] * rinv) + 0x8000u;
        unsigned y3 = __builtin_bit_cast(unsigned, o1[3] * rinv) + 0x8000u;
        uint2 w1;
        w1.x = __builtin_amdgcn_perm(y1, y0, 0x07060302u);
        w1.y = __builtin_amdgcn_perm(y3, y2, 0x07060302u);
        u16* orow = o_ws + obase + (size_t)(jbase + l15) * 512;
        *reinterpret_cast<uint2*>(orow + g * 4) = w0;
        *reinterpret_cast<uint2*>(orow + 16 + g * 4) = w1;
    };
    store_o(tA * 16, accA0, accA1, sumA);
    store_o(tB * 16, accB0, accB1, sumB);
}

// ---------------- output projection + residual ----------------
__global__ __launch_bounds__(256) void outproj(const u16* __restrict__ o_ws,
                                               const u16* __restrict__ wo_t,
                                               const float* __restrict__ pair,
                                               const float* __restrict__ bo,
                                               float* __restrict__ out) {
    __shared__ u16 As[64 * 72];
    __shared__ u16 Bs[128 * 72];
    const int tid = threadIdx.x;
    const int m0 = blockIdx.x * 64;
    const int wave = tid >> 6, lane = tid & 63;
    const int g = lane >> 4, l15 = lane & 15;

    f32x4 acc[8];
    for (int c = 0; c < 8; ++c) acc[c] = f32x4{0.f, 0.f, 0.f, 0.f};

    for (int kt = 0; kt < 8; ++kt) {
        __syncthreads();
        for (int it = 0; it < 2; ++it) {
            int L = tid + it * 256;
            int row = L >> 3, seg = L & 7;
            *reinterpret_cast<s16x8*>(&As[row * 72 + seg * 8]) =
                *reinterpret_cast<const s16x8*>(o_ws + (size_t)(m0 + row) * 512 + kt * 64 + seg * 8);
        }
        for (int it = 0; it < 4; ++it) {
            int L = tid + it * 256;
            int n = L >> 3, seg = L & 7;
            *reinterpret_cast<s16x8*>(&Bs[n * 72 + seg * 8]) =
                *reinterpret_cast<const s16x8*>(wo_t + (size_t)n * 512 + kt * 64 + seg * 8);
        }
        __syncthreads();
        for (int kk = 0; kk < 2; ++kk) {
            const s16x8 a = *reinterpret_cast<s16x8*>(&As[(wave * 16 + l15) * 72 + kk * 32 + g * 8]);
            for (int c = 0; c < 8; ++c) {
                const s16x8 b = *reinterpret_cast<s16x8*>(&Bs[(c * 16 + l15) * 72 + kk * 32 + g * 8]);
                acc[c] = __builtin_amdgcn_mfma_f32_16x16x32_bf16(a, b, acc[c], 0, 0, 0);
            }
        }
    }

    for (int c = 0; c < 8; ++c) {
        const int n = c * 16 + l15;
        const float bias = bo[n];
        for (int r = 0; r < 4; ++r) {
            const size_t row = m0 + wave * 16 + g * 4 + r;
            out[row * 128 + n] = acc[c][r] + bias + pair[row * 128 + n];
        }
    }
}

extern "C" void kernel_launch(void* const* d_in, const int* in_sizes, int n_in,
                              void* d_out, int out_size, void* d_ws, size_t ws_size,
                              hipStream_t stream) {
    const float* pair = (const float*)d_in[0];
    const float* Wq = (const float*)d_in[1];
    const float* bq = (const float*)d_in[2];
    const float* Wk = (const float*)d_in[3];
    const float* bk = (const float*)d_in[4];
    const float* Wv = (const float*)d_in[5];
    const float* bv = (const float*)d_in[6];
    const float* Wo = (const float*)d_in[7];
    const float* bo = (const float*)d_in[8];
    float* out = (float*)d_out;

    char* ws = (char*)d_ws;
    u16* o_ws  = (u16*)(ws);                       // 64 MiB
    u16* wq_t  = (u16*)(ws + 67108864);            // 128 KiB each
    u16* wk_t  = wq_t + 65536;
    u16* wv_t  = wk_t + 65536;
    u16* wo_t  = wv_t + 65536;
    u16* pairb = (u16*)(ws + 67108864 + 1048576);  // 16 MiB

    prep_all<<<5120, 256, 0, stream>>>(Wq, Wk, Wv, Wo, pair,
                                       wq_t, wk_t, wv_t, wo_t, pairb);
    fused_attn<<<4096, 512, 0, stream>>>(pairb, wq_t, wk_t, wv_t, bq, bk, bv, o_ws);
    outproj<<<1024, 256, 0, stream>>>(o_ws, wo_t, pair, bo, out);
}

// Round 10
// 115.448 us; speedup vs baseline: 1.2388x; 1.2388x over previous
//
#include <hip/hip_runtime.h>
#include <hip/hip_bf16.h>

#define NRES 256
#define DPAIR 128
#define NHEADS 16
#define DHEAD 32
#define DINNER 512

typedef unsigned short u16;
typedef __attribute__((ext_vector_type(4))) float f32x4;
typedef __attribute__((ext_vector_type(8))) short s16x8;
typedef __attribute__((ext_vector_type(4))) short s16x4;

// (1/sqrt(32)) * log2(e): folded into q so softmax can use exp2 directly.
#define QSCALE (0.17677669529663687f * 1.4426950408889634f)

__device__ __forceinline__ u16 f32_to_bf16(float f) {
    unsigned int u = __builtin_bit_cast(unsigned int, f);
    unsigned int r = (u + 0x7FFFu + ((u >> 16) & 1u)) >> 16;
    return (u16)r;
}

__device__ __forceinline__ float fast_exp2(float x) {
#if __has_builtin(__builtin_amdgcn_exp2f)
    return __builtin_amdgcn_exp2f(x);
#else
    return exp2f(x);
#endif
}

__device__ __forceinline__ f32x4 mfma_16x16x16_bf16(s16x4 a, s16x4 b, f32x4 c) {
#if __has_builtin(__builtin_amdgcn_mfma_f32_16x16x16bf16_1k)
    return __builtin_amdgcn_mfma_f32_16x16x16bf16_1k(a, b, c, 0, 0, 0);
#elif __has_builtin(__builtin_amdgcn_mfma_f32_16x16x16_bf16)
    return __builtin_amdgcn_mfma_f32_16x16x16_bf16(a, b, c, 0, 0, 0);
#else
    f32x4 d;
    asm volatile("v_mfma_f32_16x16x16_bf16 %0, %1, %2, %3"
                 : "=v"(d) : "v"(a), "v"(b), "v"(c));
    return d;
#endif
}

// async global->LDS, 16B per lane. LDS dest is wave-uniform base + lane*16.
__device__ __forceinline__ void gll16(const void* g, void* l) {
    __builtin_amdgcn_global_load_lds(
        (__attribute__((address_space(1))) unsigned int*)(uintptr_t)g,
        (__attribute__((address_space(3))) unsigned int*)(unsigned int)(uintptr_t)l,
        16, 0, 0);
}

// ---------------- prep: weight convert/transpose + pair f32->bf16 (merged) ----------------
__global__ __launch_bounds__(256) void prep_all(const float* __restrict__ Wq,
                                                const float* __restrict__ Wk,
                                                const float* __restrict__ Wv,
                                                const float* __restrict__ Wo,
                                                const float* __restrict__ pair,
                                                u16* wq_t, u16* wk_t, u16* wv_t, u16* wo_t,
                                                u16* __restrict__ pairb) {
    const int b = blockIdx.x;
    if (b < 1024) {
        int id = b * 256 + threadIdx.x;
        if (id < 3 * 65536) {
            int m = id / 65536;
            int e = id % 65536;
            int k = e >> 9, n = e & 511;
            const float* W = (m == 0) ? Wq : ((m == 1) ? Wk : Wv);
            u16* Wt = (m == 0) ? wq_t : ((m == 1) ? wk_t : wv_t);
            Wt[n * 128 + k] = f32_to_bf16(W[e]);
        } else {
            int e = id - 3 * 65536;
            int k = e >> 7, n = e & 127;
            wo_t[n * 512 + k] = f32_to_bf16(Wo[e]);
        }
    } else {
        const int id = (b - 1024) * 256 + threadIdx.x;   // 1048576 ids x 8 elems
        const float4* s = reinterpret_cast<const float4*>(pair) + (size_t)id * 2;
        const float4 v0 = s[0], v1 = s[1];
        ushort4 lo, hi;
        lo.x = f32_to_bf16(v0.x); lo.y = f32_to_bf16(v0.y);
        lo.z = f32_to_bf16(v0.z); lo.w = f32_to_bf16(v0.w);
        hi.x = f32_to_bf16(v1.x); hi.y = f32_to_bf16(v1.y);
        hi.z = f32_to_bf16(v1.z); hi.w = f32_to_bf16(v1.w);
        ushort4* d = reinterpret_cast<ushort4*>(pairb + (size_t)id * 8);
        d[0] = lo; d[1] = hi;
    }
}

// ---------------- Fused QKV-projection + triangular attention per (i,h) ----------------
// 512 threads = 8 waves. Pair rows in registers. LDS PHASE-OVERLAY:
//   phase 0/1: wS (24576B) at offset 0 — weight slices, read by QKV MFMA loop.
//   [barrier]  wS dead.
//   phase 2/3: qS (16384B) at 0, vTS (16896B) at 16384, kS (20480B) at 33280.
// Total 53760B -> 3 blocks/CU (6 waves/SIMD) from LDS alone.
// launch_bounds min-waves stays 4: (512,6) forced VGPR 56->40 and spilled to
// scratch (+255MB HBM traffic, round 9). 56 VGPR naturally fits 6 waves/SIMD.
__global__ __launch_bounds__(512, 4) void fused_attn(const u16* __restrict__ pairb,
                                                     const u16* __restrict__ wq_t,
                                                     const u16* __restrict__ wk_t,
                                                     const u16* __restrict__ wv_t,
                                                     const float* __restrict__ bq,
                                                     const float* __restrict__ bk,
                                                     const float* __restrict__ bv,
                                                     u16* __restrict__ o_ws) {
    __shared__ __align__(128) char ldsbuf[53760];
    u16* const wS  = (u16*)ldsbuf;               // [m][c][k] linear, source-XOR by (c&7)
    u16* const qS  = (u16*)ldsbuf;               // [j][c], 16B-chunk XOR-swizzled by (j&3)
    u16* const vTS = (u16*)(ldsbuf + 16384);     // [c][j] pitch 264
    u16* const kS  = (u16*)(ldsbuf + 33280);     // [j][c] pitch 40

    // XCD swizzle: the 16 h-blocks of one i stay on one XCD (pair rows L2-shared).
    const int bx = ((blockIdx.x & 7) << 9) | (blockIdx.x >> 3);
    const int i = bx >> 4, h = bx & 15;
    const int tid = threadIdx.x;
    const int wave = tid >> 6, lane = tid & 63;   // wave 0..7
    const int g = lane >> 4, l15 = lane & 15;
    const int j0 = wave * 32;

    // ---- stage W slices: 3 x 8KiB = 24 chunks, 3 per wave (async to LDS) ----
    for (int it = 0; it < 3; ++it) {
        const int chunk = wave * 3 + it;          // 0..23
        const int m = chunk >> 3;
        const int lc = chunk & 7;
        const u16* Wt = (m == 0) ? wq_t : ((m == 1) ? wk_t : wv_t);
        const int c = lc * 4 + (lane >> 4);       // 0..31 within slice
        const int col = (lane & 15) ^ (c & 7);
        gll16((const char*)(Wt + (size_t)(h * 32) * 128) + c * 256 + col * 16,
              (void*)(wS + (m * 32 + lc * 4) * 128));
    }
    // ---- pair rows straight to registers (wave-private!) ----
    s16x8 pf[2][4];
    {
        const u16* prow = pairb + (size_t)(i * 256 + j0 + l15) * 128;
        #pragma unroll
        for (int jf = 0; jf < 2; ++jf)
            #pragma unroll
            for (int kk = 0; kk < 4; ++kk)
                pf[jf][kk] = *reinterpret_cast<const s16x8*>(prow + jf * 16 * 128 + kk * 32 + g * 8);
    }
    __syncthreads();   // drains gll16 (vmcnt) + barrier

    // ---- QKV mini-GEMM: wave owns 32 j-rows x all 32 cols, K=128 ----
    f32x4 aq[2][2], ak[2][2], av[2][2];   // q/k: [cf][jf] (swapped); v: [jf][cf]
    {
        #pragma unroll
        for (int a = 0; a < 2; ++a)
            #pragma unroll
            for (int b = 0; b < 2; ++b) {
                aq[a][b] = f32x4{0.f, 0.f, 0.f, 0.f};
                ak[a][b] = f32x4{0.f, 0.f, 0.f, 0.f};
                av[a][b] = f32x4{0.f, 0.f, 0.f, 0.f};
            }
        #pragma unroll
        for (int kk = 0; kk < 4; ++kk) {
            s16x8 wf[3][2];
            #pragma unroll
            for (int m = 0; m < 3; ++m)
                #pragma unroll
                for (int cf = 0; cf < 2; ++cf) {
                    const int c = cf * 16 + l15;
                    const int ch = (kk * 4 + g) ^ (c & 7);
                    wf[m][cf] = *reinterpret_cast<s16x8*>(&wS[(m * 32 + c) * 128 + ch * 8]);
                }
            #pragma unroll
            for (int cf = 0; cf < 2; ++cf)
                #pragma unroll
                for (int jf = 0; jf < 2; ++jf) {
                    aq[cf][jf] = __builtin_amdgcn_mfma_f32_16x16x32_bf16(wf[0][cf], pf[jf][kk], aq[cf][jf], 0, 0, 0);
                    ak[cf][jf] = __builtin_amdgcn_mfma_f32_16x16x32_bf16(wf[1][cf], pf[jf][kk], ak[cf][jf], 0, 0, 0);
                    av[jf][cf] = __builtin_amdgcn_mfma_f32_16x16x32_bf16(pf[jf][kk], wf[2][cf], av[jf][cf], 0, 0, 0);
                }
        }
    }
    __syncthreads();   // wS fully read by ALL waves; qS/vTS may now overwrite it

    // ---- epilogue: write q/k/vT into (overlaid) LDS ----
    {
        // q/k lane holds [j=j0+jf*16+l15][c=cf*16+g*4+(0..3)]
        #pragma unroll
        for (int cf = 0; cf < 2; ++cf) {
            const int c = cf * 16 + g * 4;
            const float4 b4q = *reinterpret_cast<const float4*>(bq + h * 32 + c);
            const float4 b4k = *reinterpret_cast<const float4*>(bk + h * 32 + c);
            #pragma unroll
            for (int jf = 0; jf < 2; ++jf) {
                const int j = j0 + jf * 16 + l15;
                ushort4 oq, ok;
                oq.x = f32_to_bf16((aq[cf][jf][0] + b4q.x) * QSCALE);
                oq.y = f32_to_bf16((aq[cf][jf][1] + b4q.y) * QSCALE);
                oq.z = f32_to_bf16((aq[cf][jf][2] + b4q.z) * QSCALE);
                oq.w = f32_to_bf16((aq[cf][jf][3] + b4q.w) * QSCALE);
                // 16B-chunk XOR swizzle: chunk cc = 2cf + (g>>1), pos = cc ^ (j&3)
                *reinterpret_cast<ushort4*>(
                    &qS[j * 32 + (((cf << 1) + (g >> 1)) ^ (j & 3)) * 8 + (g & 1) * 4]) = oq;
                ok.x = f32_to_bf16(ak[cf][jf][0] + b4k.x);
                ok.y = f32_to_bf16(ak[cf][jf][1] + b4k.y);
                ok.z = f32_to_bf16(ak[cf][jf][2] + b4k.z);
                ok.w = f32_to_bf16(ak[cf][jf][3] + b4k.w);
                *reinterpret_cast<ushort4*>(&kS[j * 40 + c]) = ok;
            }
        }
        // v: lane holds [j=j0+jf*16+g*4+(0..3)][c=cf*16+l15] -> vTS[c][j]
        #pragma unroll
        for (int cf = 0; cf < 2; ++cf) {
            const int c = cf * 16 + l15;
            const float bvv = bv[h * 32 + c];
            #pragma unroll
            for (int jf = 0; jf < 2; ++jf) {
                const int j = j0 + jf * 16 + g * 4;
                ushort4 ov;
                ov.x = f32_to_bf16(av[jf][cf][0] + bvv);
                ov.y = f32_to_bf16(av[jf][cf][1] + bvv);
                ov.z = f32_to_bf16(av[jf][cf][2] + bvv);
                ov.w = f32_to_bf16(av[jf][cf][3] + bvv);
                *reinterpret_cast<ushort4*>(&vTS[c * 264 + j]) = ov;
            }
        }
    }
    __syncthreads();

    // ---- attention: chunks tA=wave, tB=15-wave interleaved (tA < tB always) ----
    const size_t obase = ((size_t)i * 256) * 512 + h * 32;
    const int tA = wave, tB = 15 - wave;

    const s16x8 qfA = *reinterpret_cast<const s16x8*>(
        &qS[(tA * 16 + l15) * 32 + (g ^ (l15 & 3)) * 8]);
    const s16x8 qfB = *reinterpret_cast<const s16x8*>(
        &qS[(tB * 16 + l15) * 32 + (g ^ (l15 & 3)) * 8]);

    f32x4 accA0 = {0.f, 0.f, 0.f, 0.f}, accA1 = {0.f, 0.f, 0.f, 0.f};
    f32x4 accB0 = {0.f, 0.f, 0.f, 0.f}, accB1 = {0.f, 0.f, 0.f, 0.f};
    float sumA = 0.f, sumB = 0.f;

    auto rdK = [&](int kt) {
        return *reinterpret_cast<s16x8*>(&kS[(kt * 16 + l15) * 40 + g * 8]);
    };
    auto rdV0 = [&](int kt) {
        return *reinterpret_cast<s16x4*>(&vTS[l15 * 264 + kt * 16 + g * 4]);
    };
    auto rdV1 = [&](int kt) {
        return *reinterpret_cast<s16x4*>(&vTS[(16 + l15) * 264 + kt * 16 + g * 4]);
    };
    auto tile = [&](const s16x8& kf, const s16x4& va0, const s16x4& va1,
                    const s16x8& qf, f32x4& a0, f32x4& a1, float& sm, bool dg) {
        f32x4 s = __builtin_amdgcn_mfma_f32_16x16x32_bf16(kf, qf, f32x4{0.f, 0.f, 0.f, 0.f}, 0, 0, 0);
        // s[r] = S[k = kt*16 + g*4 + r][j] (log2 domain)
        float p0, p1, p2, p3;
        if (dg) {  // diagonal tile: mask k > j
            p0 = ((g * 4 + 0) > l15) ? 0.f : fast_exp2(s[0]);
            p1 = ((g * 4 + 1) > l15) ? 0.f : fast_exp2(s[1]);
            p2 = ((g * 4 + 2) > l15) ? 0.f : fast_exp2(s[2]);
            p3 = ((g * 4 + 3) > l15) ? 0.f : fast_exp2(s[3]);
        } else {
            p0 = fast_exp2(s[0]); p1 = fast_exp2(s[1]);
            p2 = fast_exp2(s[2]); p3 = fast_exp2(s[3]);
        }
        sm += (p0 + p1) + (p2 + p3);
        unsigned e0 = __builtin_bit_cast(unsigned, p0) + 0x8000u;
        unsigned e1 = __builtin_bit_cast(unsigned, p1) + 0x8000u;
        unsigned e2 = __builtin_bit_cast(unsigned, p2) + 0x8000u;
        unsigned e3 = __builtin_bit_cast(unsigned, p3) + 0x8000u;
        uint2 pw;
        pw.x = __builtin_amdgcn_perm(e1, e0, 0x07060302u);
        pw.y = __builtin_amdgcn_perm(e3, e2, 0x07060302u);
        const s16x4 pb = __builtin_bit_cast(s16x4, pw);
        a0 = mfma_16x16x16_bf16(va0, pb, a0);
        a1 = mfma_16x16x16_bf16(va1, pb, a1);
    };

    for (int kt = 0; kt < tA; ++kt) {
        const s16x8 kf = rdK(kt);
        const s16x4 v0 = rdV0(kt), v1 = rdV1(kt);
        tile(kf, v0, v1, qfB, accB0, accB1, sumB, false);
        tile(kf, v0, v1, qfA, accA0, accA1, sumA, false);
    }
    {   // kt == tA: A's diagonal; B regular (tA < tB)
        const s16x8 kf = rdK(tA);
        const s16x4 v0 = rdV0(tA), v1 = rdV1(tA);
        tile(kf, v0, v1, qfB, accB0, accB1, sumB, false);
        tile(kf, v0, v1, qfA, accA0, accA1, sumA, true);
    }
    for (int kt = tA + 1; kt < tB; ++kt) {
        const s16x8 kf = rdK(kt);
        const s16x4 v0 = rdV0(kt), v1 = rdV1(kt);
        tile(kf, v0, v1, qfB, accB0, accB1, sumB, false);
    }
    {   // kt == tB: B's diagonal
        const s16x8 kf = rdK(tB);
        const s16x4 v0 = rdV0(tB), v1 = rdV1(tB);
        tile(kf, v0, v1, qfB, accB0, accB1, sumB, true);
    }

    auto store_o = [&](int jbase, const f32x4& o0, const f32x4& o1, float sum) {
        sum += __shfl_xor(sum, 16, 64);
        sum += __shfl_xor(sum, 32, 64);
        const float rinv = 1.0f / sum;
        unsigned x0 = __builtin_bit_cast(unsigned, o0[0] * rinv) + 0x8000u;
        unsigned x1 = __builtin_bit_cast(unsigned, o0[1] * rinv) + 0x8000u;
        unsigned x2 = __builtin_bit_cast(unsigned, o0[2] * rinv) + 0x8000u;
        unsigned x3 = __builtin_bit_cast(unsigned, o0[3] * rinv) + 0x8000u;
        uint2 w0;
        w0.x = __builtin_amdgcn_perm(x1, x0, 0x07060302u);
        w0.y = __builtin_amdgcn_perm(x3, x2, 0x07060302u);
        unsigned y0 = __builtin_bit_cast(unsigned, o1[0] * rinv) + 0x8000u;
        unsigned y1 = __builtin_bit_cast(unsigned, o1[1] * rinv) + 0x8000u;
        unsigned y2 = __builtin_bit_cast(unsigned, o1[2] * rinv) + 0x8000u;
        unsigned y3 = __builtin_bit_cast(unsigned, o1[3] * rinv) + 0x8000u;
        uint2 w1;
        w1.x = __builtin_amdgcn_perm(y1, y0, 0x07060302u);
        w1.y = __builtin_amdgcn_perm(y3, y2, 0x07060302u);
        u16* orow = o_ws + obase + (size_t)(jbase + l15) * 512;
        *reinterpret_cast<uint2*>(orow + g * 4) = w0;
        *reinterpret_cast<uint2*>(orow + 16 + g * 4) = w1;
    };
    store_o(tA * 16, accA0, accA1, sumA);
    store_o(tB * 16, accB0, accB1, sumB);
}

// ---------------- output projection + residual ----------------
__global__ __launch_bounds__(256) void outproj(const u16* __restrict__ o_ws,
                                               const u16* __restrict__ wo_t,
                                               const float* __restrict__ pair,
                                               const float* __restrict__ bo,
                                               float* __restrict__ out) {
    __shared__ u16 As[64 * 72];
    __shared__ u16 Bs[128 * 72];
    const int tid = threadIdx.x;
    const int m0 = blockIdx.x * 64;
    const int wave = tid >> 6, lane = tid & 63;
    const int g = lane >> 4, l15 = lane & 15;

    f32x4 acc[8];
    for (int c = 0; c < 8; ++c) acc[c] = f32x4{0.f, 0.f, 0.f, 0.f};

    for (int kt = 0; kt < 8; ++kt) {
        __syncthreads();
        for (int it = 0; it < 2; ++it) {
            int L = tid + it * 256;
            int row = L >> 3, seg = L & 7;
            *reinterpret_cast<s16x8*>(&As[row * 72 + seg * 8]) =
                *reinterpret_cast<const s16x8*>(o_ws + (size_t)(m0 + row) * 512 + kt * 64 + seg * 8);
        }
        for (int it = 0; it < 4; ++it) {
            int L = tid + it * 256;
            int n = L >> 3, seg = L & 7;
            *reinterpret_cast<s16x8*>(&Bs[n * 72 + seg * 8]) =
                *reinterpret_cast<const s16x8*>(wo_t + (size_t)n * 512 + kt * 64 + seg * 8);
        }
        __syncthreads();
        for (int kk = 0; kk < 2; ++kk) {
            const s16x8 a = *reinterpret_cast<s16x8*>(&As[(wave * 16 + l15) * 72 + kk * 32 + g * 8]);
            for (int c = 0; c < 8; ++c) {
                const s16x8 b = *reinterpret_cast<s16x8*>(&Bs[(c * 16 + l15) * 72 + kk * 32 + g * 8]);
                acc[c] = __builtin_amdgcn_mfma_f32_16x16x32_bf16(a, b, acc[c], 0, 0, 0);
            }
        }
    }

    for (int c = 0; c < 8; ++c) {
        const int n = c * 16 + l15;
        const float bias = bo[n];
        for (int r = 0; r < 4; ++r) {
            const size_t row = m0 + wave * 16 + g * 4 + r;
            out[row * 128 + n] = acc[c][r] + bias + pair[row * 128 + n];
        }
    }
}

extern "C" void kernel_launch(void* const* d_in, const int* in_sizes, int n_in,
                              void* d_out, int out_size, void* d_ws, size_t ws_size,
                              hipStream_t stream) {
    const float* pair = (const float*)d_in[0];
    const float* Wq = (const float*)d_in[1];
    const float* bq = (const float*)d_in[2];
    const float* Wk = (const float*)d_in[3];
    const float* bk = (const float*)d_in[4];
    const float* Wv = (const float*)d_in[5];
    const float* bv = (const float*)d_in[6];
    const float* Wo = (const float*)d_in[7];
    const float* bo = (const float*)d_in[8];
    float* out = (float*)d_out;

    char* ws = (char*)d_ws;
    u16* o_ws  = (u16*)(ws);                       // 64 MiB
    u16* wq_t  = (u16*)(ws + 67108864);            // 128 KiB each
    u16* wk_t  = wq_t + 65536;
    u16* wv_t  = wk_t + 65536;
    u16* wo_t  = wv_t + 65536;
    u16* pairb = (u16*)(ws + 67108864 + 1048576);  // 16 MiB

    prep_all<<<5120, 256, 0, stream>>>(Wq, Wk, Wv, Wo, pair,
                                       wq_t, wk_t, wv_t, wo_t, pairb);
    fused_attn<<<4096, 512, 0, stream>>>(pairb, wq_t, wk_t, wv_t, bq, bk, bv, o_ws);
    outproj<<<1024, 256, 0, stream>>>(o_ws, wo_t, pair, bo, out);
}

// Round 11
// 114.878 us; speedup vs baseline: 1.2450x; 1.0050x over previous
//
#include <hip/hip_runtime.h>
#include <hip/hip_bf16.h>

#define NRES 256
#define DPAIR 128
#define NHEADS 16
#define DHEAD 32
#define DINNER 512

typedef unsigned short u16;
typedef __attribute__((ext_vector_type(4))) float f32x4;
typedef __attribute__((ext_vector_type(8))) short s16x8;
typedef __attribute__((ext_vector_type(4))) short s16x4;

// (1/sqrt(32)) * log2(e): folded into q so softmax can use exp2 directly.
#define QSCALE (0.17677669529663687f * 1.4426950408889634f)

__device__ __forceinline__ u16 f32_to_bf16(float f) {
    unsigned int u = __builtin_bit_cast(unsigned int, f);
    unsigned int r = (u + 0x7FFFu + ((u >> 16) & 1u)) >> 16;
    return (u16)r;
}

// pack two f32 -> bf16 pair (round-half-up) via v_perm: {bf16(a) | bf16(b)<<16}
__device__ __forceinline__ unsigned pk2(float a, float b) {
    unsigned ua = __builtin_bit_cast(unsigned, a) + 0x8000u;
    unsigned ub = __builtin_bit_cast(unsigned, b) + 0x8000u;
    return __builtin_amdgcn_perm(ub, ua, 0x07060302u);
}

__device__ __forceinline__ float fast_exp2(float x) {
#if __has_builtin(__builtin_amdgcn_exp2f)
    return __builtin_amdgcn_exp2f(x);
#else
    return exp2f(x);
#endif
}

__device__ __forceinline__ f32x4 mfma_16x16x16_bf16(s16x4 a, s16x4 b, f32x4 c) {
#if __has_builtin(__builtin_amdgcn_mfma_f32_16x16x16bf16_1k)
    return __builtin_amdgcn_mfma_f32_16x16x16bf16_1k(a, b, c, 0, 0, 0);
#elif __has_builtin(__builtin_amdgcn_mfma_f32_16x16x16_bf16)
    return __builtin_amdgcn_mfma_f32_16x16x16_bf16(a, b, c, 0, 0, 0);
#else
    f32x4 d;
    asm volatile("v_mfma_f32_16x16x16_bf16 %0, %1, %2, %3"
                 : "=v"(d) : "v"(a), "v"(b), "v"(c));
    return d;
#endif
}

// async global->LDS, 16B per lane. LDS dest is wave-uniform base + lane*16.
__device__ __forceinline__ void gll16(const void* g, void* l) {
    __builtin_amdgcn_global_load_lds(
        (__attribute__((address_space(1))) unsigned int*)(uintptr_t)g,
        (__attribute__((address_space(3))) unsigned int*)(unsigned int)(uintptr_t)l,
        16, 0, 0);
}

// ---------------- prep: weight convert/transpose + pair f32->bf16 (merged) ----------------
__global__ __launch_bounds__(256) void prep_all(const float* __restrict__ Wq,
                                                const float* __restrict__ Wk,
                                                const float* __restrict__ Wv,
                                                const float* __restrict__ Wo,
                                                const float* __restrict__ pair,
                                                u16* wq_t, u16* wk_t, u16* wv_t, u16* wo_t,
                                                u16* __restrict__ pairb) {
    const int b = blockIdx.x;
    if (b < 1024) {
        int id = b * 256 + threadIdx.x;
        if (id < 3 * 65536) {
            int m = id / 65536;
            int e = id % 65536;
            int k = e >> 9, n = e & 511;
            const float* W = (m == 0) ? Wq : ((m == 1) ? Wk : Wv);
            u16* Wt = (m == 0) ? wq_t : ((m == 1) ? wk_t : wv_t);
            Wt[n * 128 + k] = f32_to_bf16(W[e]);
        } else {
            int e = id - 3 * 65536;
            int k = e >> 7, n = e & 127;
            wo_t[n * 512 + k] = f32_to_bf16(Wo[e]);
        }
    } else {
        const int id = (b - 1024) * 256 + threadIdx.x;   // 1048576 ids x 8 elems
        const float4* s = reinterpret_cast<const float4*>(pair) + (size_t)id * 2;
        const float4 v0 = s[0], v1 = s[1];
        ushort4 lo, hi;
        lo.x = f32_to_bf16(v0.x); lo.y = f32_to_bf16(v0.y);
        lo.z = f32_to_bf16(v0.z); lo.w = f32_to_bf16(v0.w);
        hi.x = f32_to_bf16(v1.x); hi.y = f32_to_bf16(v1.y);
        hi.z = f32_to_bf16(v1.z); hi.w = f32_to_bf16(v1.w);
        ushort4* d = reinterpret_cast<ushort4*>(pairb + (size_t)id * 8);
        d[0] = lo; d[1] = hi;
    }
}

// ---------------- Fused QKV-projection + triangular attention per (i,h) ----------------
// 512 threads = 8 waves. Pair rows in registers. LDS PHASE-OVERLAY (53760B,
// 3 blocks/CU). Row-sum computed ON THE MFMA PIPE via a constant-ones fragment
// (kills per-tile fadds + all cross-lane shuffles).
__global__ __launch_bounds__(512, 4) void fused_attn(const u16* __restrict__ pairb,
                                                     const u16* __restrict__ wq_t,
                                                     const u16* __restrict__ wk_t,
                                                     const u16* __restrict__ wv_t,
                                                     const float* __restrict__ bq,
                                                     const float* __restrict__ bk,
                                                     const float* __restrict__ bv,
                                                     u16* __restrict__ o_ws) {
    __shared__ __align__(128) char ldsbuf[53760];
    u16* const wS  = (u16*)ldsbuf;               // [m][c][k] linear, source-XOR by (c&7)
    u16* const qS  = (u16*)ldsbuf;               // [j][c], 16B-chunk XOR-swizzled by (j&3)
    u16* const vTS = (u16*)(ldsbuf + 16384);     // [c][j] pitch 264
    u16* const kS  = (u16*)(ldsbuf + 33280);     // [j][c] pitch 40

    // XCD swizzle: the 16 h-blocks of one i stay on one XCD (pair rows L2-shared).
    const int bx = ((blockIdx.x & 7) << 9) | (blockIdx.x >> 3);
    const int i = bx >> 4, h = bx & 15;
    const int tid = threadIdx.x;
    const int wave = tid >> 6, lane = tid & 63;   // wave 0..7
    const int g = lane >> 4, l15 = lane & 15;
    const int j0 = wave * 32;

    // ---- stage W slices: 3 x 8KiB = 24 chunks, 3 per wave (async to LDS) ----
    for (int it = 0; it < 3; ++it) {
        const int chunk = wave * 3 + it;          // 0..23
        const int m = chunk >> 3;
        const int lc = chunk & 7;
        const u16* Wt = (m == 0) ? wq_t : ((m == 1) ? wk_t : wv_t);
        const int c = lc * 4 + (lane >> 4);       // 0..31 within slice
        const int col = (lane & 15) ^ (c & 7);
        gll16((const char*)(Wt + (size_t)(h * 32) * 128) + c * 256 + col * 16,
              (void*)(wS + (m * 32 + lc * 4) * 128));
    }
    // ---- pair rows straight to registers (wave-private!) ----
    s16x8 pf[2][4];
    {
        const u16* prow = pairb + (size_t)(i * 256 + j0 + l15) * 128;
        #pragma unroll
        for (int jf = 0; jf < 2; ++jf)
            #pragma unroll
            for (int kk = 0; kk < 4; ++kk)
                pf[jf][kk] = *reinterpret_cast<const s16x8*>(prow + jf * 16 * 128 + kk * 32 + g * 8);
    }
    __syncthreads();   // drains gll16 (vmcnt) + barrier

    // ---- QKV mini-GEMM: wave owns 32 j-rows x all 32 cols, K=128 ----
    f32x4 aq[2][2], ak[2][2], av[2][2];   // q/k: [cf][jf] (swapped); v: [jf][cf]
    {
        #pragma unroll
        for (int a = 0; a < 2; ++a)
            #pragma unroll
            for (int b = 0; b < 2; ++b) {
                aq[a][b] = f32x4{0.f, 0.f, 0.f, 0.f};
                ak[a][b] = f32x4{0.f, 0.f, 0.f, 0.f};
                av[a][b] = f32x4{0.f, 0.f, 0.f, 0.f};
            }
        #pragma unroll
        for (int kk = 0; kk < 4; ++kk) {
            s16x8 wf[3][2];
            #pragma unroll
            for (int m = 0; m < 3; ++m)
                #pragma unroll
                for (int cf = 0; cf < 2; ++cf) {
                    const int c = cf * 16 + l15;
                    const int ch = (kk * 4 + g) ^ (c & 7);
                    wf[m][cf] = *reinterpret_cast<s16x8*>(&wS[(m * 32 + c) * 128 + ch * 8]);
                }
            #pragma unroll
            for (int cf = 0; cf < 2; ++cf)
                #pragma unroll
                for (int jf = 0; jf < 2; ++jf) {
                    aq[cf][jf] = __builtin_amdgcn_mfma_f32_16x16x32_bf16(wf[0][cf], pf[jf][kk], aq[cf][jf], 0, 0, 0);
                    ak[cf][jf] = __builtin_amdgcn_mfma_f32_16x16x32_bf16(wf[1][cf], pf[jf][kk], ak[cf][jf], 0, 0, 0);
                    av[jf][cf] = __builtin_amdgcn_mfma_f32_16x16x32_bf16(pf[jf][kk], wf[2][cf], av[jf][cf], 0, 0, 0);
                }
        }
    }
    __syncthreads();   // wS fully read by ALL waves; qS/vTS may now overwrite it

    // ---- epilogue: write q/k/vT into (overlaid) LDS (pk2 pair-packs) ----
    {
        // q/k lane holds [j=j0+jf*16+l15][c=cf*16+g*4+(0..3)]
        #pragma unroll
        for (int cf = 0; cf < 2; ++cf) {
            const int c = cf * 16 + g * 4;
            const float4 b4q = *reinterpret_cast<const float4*>(bq + h * 32 + c);
            const float4 b4k = *reinterpret_cast<const float4*>(bk + h * 32 + c);
            #pragma unroll
            for (int jf = 0; jf < 2; ++jf) {
                const int j = j0 + jf * 16 + l15;
                uint2 oq, ok;
                oq.x = pk2((aq[cf][jf][0] + b4q.x) * QSCALE, (aq[cf][jf][1] + b4q.y) * QSCALE);
                oq.y = pk2((aq[cf][jf][2] + b4q.z) * QSCALE, (aq[cf][jf][3] + b4q.w) * QSCALE);
                // 16B-chunk XOR swizzle: chunk cc = 2cf + (g>>1), pos = cc ^ (j&3)
                *reinterpret_cast<uint2*>(
                    &qS[j * 32 + (((cf << 1) + (g >> 1)) ^ (j & 3)) * 8 + (g & 1) * 4]) = oq;
                ok.x = pk2(ak[cf][jf][0] + b4k.x, ak[cf][jf][1] + b4k.y);
                ok.y = pk2(ak[cf][jf][2] + b4k.z, ak[cf][jf][3] + b4k.w);
                *reinterpret_cast<uint2*>(&kS[j * 40 + c]) = ok;
            }
        }
        // v: lane holds [j=j0+jf*16+g*4+(0..3)][c=cf*16+l15] -> vTS[c][j]
        #pragma unroll
        for (int cf = 0; cf < 2; ++cf) {
            const int c = cf * 16 + l15;
            const float bvv = bv[h * 32 + c];
            #pragma unroll
            for (int jf = 0; jf < 2; ++jf) {
                const int j = j0 + jf * 16 + g * 4;
                uint2 ov;
                ov.x = pk2(av[jf][cf][0] + bvv, av[jf][cf][1] + bvv);
                ov.y = pk2(av[jf][cf][2] + bvv, av[jf][cf][3] + bvv);
                *reinterpret_cast<uint2*>(&vTS[c * 264 + j]) = ov;
            }
        }
    }
    __syncthreads();

    // ---- attention: chunks tA=wave, tB=15-wave interleaved (tA < tB always) ----
    const size_t obase = ((size_t)i * 256) * 512 + h * 32;
    const int tA = wave, tB = 15 - wave;

    const s16x8 qfA = *reinterpret_cast<const s16x8*>(
        &qS[(tA * 16 + l15) * 32 + (g ^ (l15 & 3)) * 8]);
    const s16x8 qfB = *reinterpret_cast<const s16x8*>(
        &qS[(tB * 16 + l15) * 32 + (g ^ (l15 & 3)) * 8]);

    // ones fragment: row-sum accumulates on the MFMA pipe (o2 = ones^T @ P)
    const s16x4 vone = {(short)0x3F80, (short)0x3F80, (short)0x3F80, (short)0x3F80};

    f32x4 accA0 = {0.f, 0.f, 0.f, 0.f}, accA1 = {0.f, 0.f, 0.f, 0.f}, accA2 = {0.f, 0.f, 0.f, 0.f};
    f32x4 accB0 = {0.f, 0.f, 0.f, 0.f}, accB1 = {0.f, 0.f, 0.f, 0.f}, accB2 = {0.f, 0.f, 0.f, 0.f};

    auto rdK = [&](int kt) {
        return *reinterpret_cast<s16x8*>(&kS[(kt * 16 + l15) * 40 + g * 8]);
    };
    auto rdV0 = [&](int kt) {
        return *reinterpret_cast<s16x4*>(&vTS[l15 * 264 + kt * 16 + g * 4]);
    };
    auto rdV1 = [&](int kt) {
        return *reinterpret_cast<s16x4*>(&vTS[(16 + l15) * 264 + kt * 16 + g * 4]);
    };
    auto tile = [&](const s16x8& kf, const s16x4& va0, const s16x4& va1,
                    const s16x8& qf, f32x4& a0, f32x4& a1, f32x4& a2, bool dg) {
        f32x4 s = __builtin_amdgcn_mfma_f32_16x16x32_bf16(kf, qf, f32x4{0.f, 0.f, 0.f, 0.f}, 0, 0, 0);
        // s[r] = S[k = kt*16 + g*4 + r][j] (log2 domain)
        float p0, p1, p2, p3;
        if (dg) {  // diagonal tile: mask k > j
            p0 = ((g * 4 + 0) > l15) ? 0.f : fast_exp2(s[0]);
            p1 = ((g * 4 + 1) > l15) ? 0.f : fast_exp2(s[1]);
            p2 = ((g * 4 + 2) > l15) ? 0.f : fast_exp2(s[2]);
            p3 = ((g * 4 + 3) > l15) ? 0.f : fast_exp2(s[3]);
        } else {
            p0 = fast_exp2(s[0]); p1 = fast_exp2(s[1]);
            p2 = fast_exp2(s[2]); p3 = fast_exp2(s[3]);
        }
        uint2 pw;
        pw.x = pk2(p0, p1);
        pw.y = pk2(p2, p3);
        const s16x4 pb = __builtin_bit_cast(s16x4, pw);
        a0 = mfma_16x16x16_bf16(va0, pb, a0);
        a1 = mfma_16x16x16_bf16(va1, pb, a1);
        a2 = mfma_16x16x16_bf16(vone, pb, a2);   // row-sum (all k reduced in-MFMA)
    };

    __builtin_amdgcn_s_setprio(1);
    for (int kt = 0; kt < tA; ++kt) {
        const s16x8 kf = rdK(kt);
        const s16x4 v0 = rdV0(kt), v1 = rdV1(kt);
        tile(kf, v0, v1, qfB, accB0, accB1, accB2, false);
        tile(kf, v0, v1, qfA, accA0, accA1, accA2, false);
    }
    {   // kt == tA: A's diagonal; B regular (tA < tB)
        const s16x8 kf = rdK(tA);
        const s16x4 v0 = rdV0(tA), v1 = rdV1(tA);
        tile(kf, v0, v1, qfB, accB0, accB1, accB2, false);
        tile(kf, v0, v1, qfA, accA0, accA1, accA2, true);
    }
    for (int kt = tA + 1; kt < tB; ++kt) {
        const s16x8 kf = rdK(kt);
        const s16x4 v0 = rdV0(kt), v1 = rdV1(kt);
        tile(kf, v0, v1, qfB, accB0, accB1, accB2, false);
    }
    {   // kt == tB: B's diagonal
        const s16x8 kf = rdK(tB);
        const s16x4 v0 = rdV0(tB), v1 = rdV1(tB);
        tile(kf, v0, v1, qfB, accB0, accB1, accB2, true);
    }
    __builtin_amdgcn_s_setprio(0);

    auto store_o = [&](int jbase, const f32x4& o0, const f32x4& o1, float sum) {
        const float rinv = 1.0f / sum;    // sum identical across lanes' regs for this j=l15
        uint2 w0, w1;
        w0.x = pk2(o0[0] * rinv, o0[1] * rinv);
        w0.y = pk2(o0[2] * rinv, o0[3] * rinv);
        w1.x = pk2(o1[0] * rinv, o1[1] * rinv);
        w1.y = pk2(o1[2] * rinv, o1[3] * rinv);
        u16* orow = o_ws + obase + (size_t)(jbase + l15) * 512;
        *reinterpret_cast<uint2*>(orow + g * 4) = w0;
        *reinterpret_cast<uint2*>(orow + 16 + g * 4) = w1;
    };
    store_o(tA * 16, accA0, accA1, accA2[0]);
    store_o(tB * 16, accB0, accB1, accB2[0]);
}

// ---------------- output projection + residual ----------------
// Block decode keeps each 64-row tile on the XCD whose fused_attn blocks
// produced those o rows (producer XCD = i>>5 = (b'>>7)).
__global__ __launch_bounds__(256) void outproj(const u16* __restrict__ o_ws,
                                               const u16* __restrict__ wo_t,
                                               const float* __restrict__ pair,
                                               const float* __restrict__ bo,
                                               float* __restrict__ out) {
    __shared__ u16 As[64 * 72];
    __shared__ u16 Bs[128 * 72];
    const int tid = threadIdx.x;
    const int d = blockIdx.x;
    const int bb = ((d & 7) << 7) | (d >> 3);    // (bb>>7) == d&7 == XCD
    const int m0 = bb * 64;
    const int wave = tid >> 6, lane = tid & 63;
    const int g = lane >> 4, l15 = lane & 15;

    f32x4 acc[8];
    for (int c = 0; c < 8; ++c) acc[c] = f32x4{0.f, 0.f, 0.f, 0.f};

    for (int kt = 0; kt < 8; ++kt) {
        __syncthreads();
        for (int it = 0; it < 2; ++it) {
            int L = tid + it * 256;
            int row = L >> 3, seg = L & 7;
            *reinterpret_cast<s16x8*>(&As[row * 72 + seg * 8]) =
                *reinterpret_cast<const s16x8*>(o_ws + (size_t)(m0 + row) * 512 + kt * 64 + seg * 8);
        }
        for (int it = 0; it < 4; ++it) {
            int L = tid + it * 256;
            int n = L >> 3, seg = L & 7;
            *reinterpret_cast<s16x8*>(&Bs[n * 72 + seg * 8]) =
                *reinterpret_cast<const s16x8*>(wo_t + (size_t)n * 512 + kt * 64 + seg * 8);
        }
        __syncthreads();
        for (int kk = 0; kk < 2; ++kk) {
            const s16x8 a = *reinterpret_cast<s16x8*>(&As[(wave * 16 + l15) * 72 + kk * 32 + g * 8]);
            for (int c = 0; c < 8; ++c) {
                const s16x8 b = *reinterpret_cast<s16x8*>(&Bs[(c * 16 + l15) * 72 + kk * 32 + g * 8]);
                acc[c] = __builtin_amdgcn_mfma_f32_16x16x32_bf16(a, b, acc[c], 0, 0, 0);
            }
        }
    }

    for (int c = 0; c < 8; ++c) {
        const int n = c * 16 + l15;
        const float bias = bo[n];
        for (int r = 0; r < 4; ++r) {
            const size_t row = m0 + wave * 16 + g * 4 + r;
            out[row * 128 + n] = acc[c][r] + bias + pair[row * 128 + n];
        }
    }
}

extern "C" void kernel_launch(void* const* d_in, const int* in_sizes, int n_in,
                              void* d_out, int out_size, void* d_ws, size_t ws_size,
                              hipStream_t stream) {
    const float* pair = (const float*)d_in[0];
    const float* Wq = (const float*)d_in[1];
    const float* bq = (const float*)d_in[2];
    const float* Wk = (const float*)d_in[3];
    const float* bk = (const float*)d_in[4];
    const float* Wv = (const float*)d_in[5];
    const float* bv = (const float*)d_in[6];
    const float* Wo = (const float*)d_in[7];
    const float* bo = (const float*)d_in[8];
    float* out = (float*)d_out;

    char* ws = (char*)d_ws;
    u16* o_ws  = (u16*)(ws);                       // 64 MiB
    u16* wq_t  = (u16*)(ws + 67108864);            // 128 KiB each
    u16* wk_t  = wq_t + 65536;
    u16* wv_t  = wk_t + 65536;
    u16* wo_t  = wv_t + 65536;
    u16* pairb = (u16*)(ws + 67108864 + 1048576);  // 16 MiB

    prep_all<<<5120, 256, 0, stream>>>(Wq, Wk, Wv, Wo, pair,
                                       wq_t, wk_t, wv_t, wo_t, pairb);
    fused_attn<<<4096, 512, 0, stream>>>(pairb, wq_t, wk_t, wv_t, bq, bk, bv, o_ws);
    outproj<<<1024, 256, 0, stream>>>(o_ws, wo_t, pair, bo, out);
}

// Round 12
// 114.856 us; speedup vs baseline: 1.2452x; 1.0002x over previous
//
#include <hip/hip_runtime.h>
#include <hip/hip_bf16.h>

#define NRES 256
#define DPAIR 128
#define NHEADS 16
#define DHEAD 32
#define DINNER 512

typedef unsigned short u16;
typedef __attribute__((ext_vector_type(4))) float f32x4;
typedef __attribute__((ext_vector_type(8))) short s16x8;
typedef __attribute__((ext_vector_type(4))) short s16x4;

// (1/sqrt(32)) * log2(e): folded into q so softmax can use exp2 directly.
#define QSCALE (0.17677669529663687f * 1.4426950408889634f)

// single-instruction 2^x (v_exp_f32) from the ROCm device library.
extern "C" __device__ float __ocml_native_exp2_f32(float);
__device__ __forceinline__ float fast_exp2(float x) { return __ocml_native_exp2_f32(x); }

__device__ __forceinline__ u16 f32_to_bf16(float f) {
    unsigned int u = __builtin_bit_cast(unsigned int, f);
    unsigned int r = (u + 0x7FFFu + ((u >> 16) & 1u)) >> 16;
    return (u16)r;
}

// pack two f32 -> bf16 pair (round-half-up) via v_perm: {bf16(a) | bf16(b)<<16}
__device__ __forceinline__ unsigned pk2(float a, float b) {
    unsigned ua = __builtin_bit_cast(unsigned, a) + 0x8000u;
    unsigned ub = __builtin_bit_cast(unsigned, b) + 0x8000u;
    return __builtin_amdgcn_perm(ub, ua, 0x07060302u);
}

__device__ __forceinline__ f32x4 mfma_16x16x16_bf16(s16x4 a, s16x4 b, f32x4 c) {
#if __has_builtin(__builtin_amdgcn_mfma_f32_16x16x16bf16_1k)
    return __builtin_amdgcn_mfma_f32_16x16x16bf16_1k(a, b, c, 0, 0, 0);
#elif __has_builtin(__builtin_amdgcn_mfma_f32_16x16x16_bf16)
    return __builtin_amdgcn_mfma_f32_16x16x16_bf16(a, b, c, 0, 0, 0);
#else
    f32x4 d;
    asm volatile("v_mfma_f32_16x16x16_bf16 %0, %1, %2, %3"
                 : "=v"(d) : "v"(a), "v"(b), "v"(c));
    return d;
#endif
}

// async global->LDS, 16B per lane. LDS dest is wave-uniform base + lane*16.
__device__ __forceinline__ void gll16(const void* g, void* l) {
    __builtin_amdgcn_global_load_lds(
        (__attribute__((address_space(1))) unsigned int*)(uintptr_t)g,
        (__attribute__((address_space(3))) unsigned int*)(unsigned int)(uintptr_t)l,
        16, 0, 0);
}

// ---------------- prep: weight convert/transpose + pair f32->bf16 (merged) ----------------
__global__ __launch_bounds__(256) void prep_all(const float* __restrict__ Wq,
                                                const float* __restrict__ Wk,
                                                const float* __restrict__ Wv,
                                                const float* __restrict__ Wo,
                                                const float* __restrict__ pair,
                                                u16* wq_t, u16* wk_t, u16* wv_t, u16* wo_t,
                                                u16* __restrict__ pairb) {
    const int b = blockIdx.x;
    if (b < 1024) {
        int id = b * 256 + threadIdx.x;
        if (id < 3 * 65536) {
            int m = id / 65536;
            int e = id % 65536;
            int k = e >> 9, n = e & 511;
            const float* W = (m == 0) ? Wq : ((m == 1) ? Wk : Wv);
            u16* Wt = (m == 0) ? wq_t : ((m == 1) ? wk_t : wv_t);
            Wt[n * 128 + k] = f32_to_bf16(W[e]);
        } else {
            int e = id - 3 * 65536;
            int k = e >> 7, n = e & 127;
            wo_t[n * 512 + k] = f32_to_bf16(Wo[e]);
        }
    } else {
        const int id = (b - 1024) * 256 + threadIdx.x;   // 1048576 ids x 8 elems
        const float4* s = reinterpret_cast<const float4*>(pair) + (size_t)id * 2;
        const float4 v0 = s[0], v1 = s[1];
        ushort4 lo, hi;
        lo.x = f32_to_bf16(v0.x); lo.y = f32_to_bf16(v0.y);
        lo.z = f32_to_bf16(v0.z); lo.w = f32_to_bf16(v0.w);
        hi.x = f32_to_bf16(v1.x); hi.y = f32_to_bf16(v1.y);
        hi.z = f32_to_bf16(v1.z); hi.w = f32_to_bf16(v1.w);
        ushort4* d = reinterpret_cast<ushort4*>(pairb + (size_t)id * 8);
        d[0] = lo; d[1] = hi;
    }
}

// ---------------- Fused QKV-projection + triangular attention per (i,h) ----------------
// 512 threads = 8 waves. Pair rows in registers. LDS PHASE-OVERLAY (53760B,
// 3 blocks/CU). Row-sum on the MFMA pipe via constant-ones fragment.
__global__ __launch_bounds__(512, 4) void fused_attn(const u16* __restrict__ pairb,
                                                     const u16* __restrict__ wq_t,
                                                     const u16* __restrict__ wk_t,
                                                     const u16* __restrict__ wv_t,
                                                     const float* __restrict__ bq,
                                                     const float* __restrict__ bk,
                                                     const float* __restrict__ bv,
                                                     u16* __restrict__ o_ws) {
    __shared__ __align__(128) char ldsbuf[53760];
    u16* const wS  = (u16*)ldsbuf;               // [m][c][k] linear, source-XOR by (c&7)
    u16* const qS  = (u16*)ldsbuf;               // [j][c], 16B-chunk XOR-swizzled by (j&3)
    u16* const vTS = (u16*)(ldsbuf + 16384);     // [c][j] pitch 264
    u16* const kS  = (u16*)(ldsbuf + 33280);     // [j][c] pitch 40

    // XCD swizzle: the 16 h-blocks of one i stay on one XCD (pair rows L2-shared).
    const int bx = ((blockIdx.x & 7) << 9) | (blockIdx.x >> 3);
    const int i = bx >> 4, h = bx & 15;
    const int tid = threadIdx.x;
    const int wave = tid >> 6, lane = tid & 63;   // wave 0..7
    const int g = lane >> 4, l15 = lane & 15;
    const int j0 = wave * 32;

    // ---- stage W slices: 3 x 8KiB = 24 chunks, 3 per wave (async to LDS) ----
    for (int it = 0; it < 3; ++it) {
        const int chunk = wave * 3 + it;          // 0..23
        const int m = chunk >> 3;
        const int lc = chunk & 7;
        const u16* Wt = (m == 0) ? wq_t : ((m == 1) ? wk_t : wv_t);
        const int c = lc * 4 + (lane >> 4);       // 0..31 within slice
        const int col = (lane & 15) ^ (c & 7);
        gll16((const char*)(Wt + (size_t)(h * 32) * 128) + c * 256 + col * 16,
              (void*)(wS + (m * 32 + lc * 4) * 128));
    }
    // ---- pair rows straight to registers (wave-private!) ----
    s16x8 pf[2][4];
    {
        const u16* prow = pairb + (size_t)(i * 256 + j0 + l15) * 128;
        #pragma unroll
        for (int jf = 0; jf < 2; ++jf)
            #pragma unroll
            for (int kk = 0; kk < 4; ++kk)
                pf[jf][kk] = *reinterpret_cast<const s16x8*>(prow + jf * 16 * 128 + kk * 32 + g * 8);
    }
    __syncthreads();   // drains gll16 (vmcnt) + barrier

    // ---- QKV mini-GEMM: wave owns 32 j-rows x all 32 cols, K=128 ----
    f32x4 aq[2][2], ak[2][2], av[2][2];   // q/k: [cf][jf] (swapped); v: [jf][cf]
    {
        #pragma unroll
        for (int a = 0; a < 2; ++a)
            #pragma unroll
            for (int b = 0; b < 2; ++b) {
                aq[a][b] = f32x4{0.f, 0.f, 0.f, 0.f};
                ak[a][b] = f32x4{0.f, 0.f, 0.f, 0.f};
                av[a][b] = f32x4{0.f, 0.f, 0.f, 0.f};
            }
        #pragma unroll
        for (int kk = 0; kk < 4; ++kk) {
            s16x8 wf[3][2];
            #pragma unroll
            for (int m = 0; m < 3; ++m)
                #pragma unroll
                for (int cf = 0; cf < 2; ++cf) {
                    const int c = cf * 16 + l15;
                    const int ch = (kk * 4 + g) ^ (c & 7);
                    wf[m][cf] = *reinterpret_cast<s16x8*>(&wS[(m * 32 + c) * 128 + ch * 8]);
                }
            #pragma unroll
            for (int cf = 0; cf < 2; ++cf)
                #pragma unroll
                for (int jf = 0; jf < 2; ++jf) {
                    aq[cf][jf] = __builtin_amdgcn_mfma_f32_16x16x32_bf16(wf[0][cf], pf[jf][kk], aq[cf][jf], 0, 0, 0);
                    ak[cf][jf] = __builtin_amdgcn_mfma_f32_16x16x32_bf16(wf[1][cf], pf[jf][kk], ak[cf][jf], 0, 0, 0);
                    av[jf][cf] = __builtin_amdgcn_mfma_f32_16x16x32_bf16(pf[jf][kk], wf[2][cf], av[jf][cf], 0, 0, 0);
                }
        }
    }
    __syncthreads();   // wS fully read by ALL waves; qS/vTS may now overwrite it

    // ---- epilogue: write q/k/vT into (overlaid) LDS (pk2 pair-packs) ----
    {
        // q/k lane holds [j=j0+jf*16+l15][c=cf*16+g*4+(0..3)]
        #pragma unroll
        for (int cf = 0; cf < 2; ++cf) {
            const int c = cf * 16 + g * 4;
            const float4 b4q = *reinterpret_cast<const float4*>(bq + h * 32 + c);
            const float4 b4k = *reinterpret_cast<const float4*>(bk + h * 32 + c);
            #pragma unroll
            for (int jf = 0; jf < 2; ++jf) {
                const int j = j0 + jf * 16 + l15;
                uint2 oq, ok;
                oq.x = pk2((aq[cf][jf][0] + b4q.x) * QSCALE, (aq[cf][jf][1] + b4q.y) * QSCALE);
                oq.y = pk2((aq[cf][jf][2] + b4q.z) * QSCALE, (aq[cf][jf][3] + b4q.w) * QSCALE);
                // 16B-chunk XOR swizzle: chunk cc = 2cf + (g>>1), pos = cc ^ (j&3)
                *reinterpret_cast<uint2*>(
                    &qS[j * 32 + (((cf << 1) + (g >> 1)) ^ (j & 3)) * 8 + (g & 1) * 4]) = oq;
                ok.x = pk2(ak[cf][jf][0] + b4k.x, ak[cf][jf][1] + b4k.y);
                ok.y = pk2(ak[cf][jf][2] + b4k.z, ak[cf][jf][3] + b4k.w);
                *reinterpret_cast<uint2*>(&kS[j * 40 + c]) = ok;
            }
        }
        // v: lane holds [j=j0+jf*16+g*4+(0..3)][c=cf*16+l15] -> vTS[c][j]
        #pragma unroll
        for (int cf = 0; cf < 2; ++cf) {
            const int c = cf * 16 + l15;
            const float bvv = bv[h * 32 + c];
            #pragma unroll
            for (int jf = 0; jf < 2; ++jf) {
                const int j = j0 + jf * 16 + g * 4;
                uint2 ov;
                ov.x = pk2(av[jf][cf][0] + bvv, av[jf][cf][1] + bvv);
                ov.y = pk2(av[jf][cf][2] + bvv, av[jf][cf][3] + bvv);
                *reinterpret_cast<uint2*>(&vTS[c * 264 + j]) = ov;
            }
        }
    }
    __syncthreads();

    // ---- attention: chunks tA=wave, tB=15-wave interleaved (tA < tB always) ----
    const size_t obase = ((size_t)i * 256) * 512 + h * 32;
    const int tA = wave, tB = 15 - wave;

    const s16x8 qfA = *reinterpret_cast<const s16x8*>(
        &qS[(tA * 16 + l15) * 32 + (g ^ (l15 & 3)) * 8]);
    const s16x8 qfB = *reinterpret_cast<const s16x8*>(
        &qS[(tB * 16 + l15) * 32 + (g ^ (l15 & 3)) * 8]);

    // ones fragment: row-sum accumulates on the MFMA pipe (o2 = ones^T @ P)
    const s16x4 vone = {(short)0x3F80, (short)0x3F80, (short)0x3F80, (short)0x3F80};

    f32x4 accA0 = {0.f, 0.f, 0.f, 0.f}, accA1 = {0.f, 0.f, 0.f, 0.f}, accA2 = {0.f, 0.f, 0.f, 0.f};
    f32x4 accB0 = {0.f, 0.f, 0.f, 0.f}, accB1 = {0.f, 0.f, 0.f, 0.f}, accB2 = {0.f, 0.f, 0.f, 0.f};

    auto rdK = [&](int kt) {
        return *reinterpret_cast<s16x8*>(&kS[(kt * 16 + l15) * 40 + g * 8]);
    };
    auto rdV0 = [&](int kt) {
        return *reinterpret_cast<s16x4*>(&vTS[l15 * 264 + kt * 16 + g * 4]);
    };
    auto rdV1 = [&](int kt) {
        return *reinterpret_cast<s16x4*>(&vTS[(16 + l15) * 264 + kt * 16 + g * 4]);
    };
    auto tile = [&](const s16x8& kf, const s16x4& va0, const s16x4& va1,
                    const s16x8& qf, f32x4& a0, f32x4& a1, f32x4& a2, bool dg) {
        f32x4 s = __builtin_amdgcn_mfma_f32_16x16x32_bf16(kf, qf, f32x4{0.f, 0.f, 0.f, 0.f}, 0, 0, 0);
        // s[r] = S[k = kt*16 + g*4 + r][j] (log2 domain)
        float p0, p1, p2, p3;
        if (dg) {  // diagonal tile: mask k > j
            p0 = ((g * 4 + 0) > l15) ? 0.f : fast_exp2(s[0]);
            p1 = ((g * 4 + 1) > l15) ? 0.f : fast_exp2(s[1]);
            p2 = ((g * 4 + 2) > l15) ? 0.f : fast_exp2(s[2]);
            p3 = ((g * 4 + 3) > l15) ? 0.f : fast_exp2(s[3]);
        } else {
            p0 = fast_exp2(s[0]); p1 = fast_exp2(s[1]);
            p2 = fast_exp2(s[2]); p3 = fast_exp2(s[3]);
        }
        uint2 pw;
        pw.x = pk2(p0, p1);
        pw.y = pk2(p2, p3);
        const s16x4 pb = __builtin_bit_cast(s16x4, pw);
        a0 = mfma_16x16x16_bf16(va0, pb, a0);
        a1 = mfma_16x16x16_bf16(va1, pb, a1);
        a2 = mfma_16x16x16_bf16(vone, pb, a2);   // row-sum (all k reduced in-MFMA)
    };

    __builtin_amdgcn_s_setprio(1);
    for (int kt = 0; kt < tA; ++kt) {
        const s16x8 kf = rdK(kt);
        const s16x4 v0 = rdV0(kt), v1 = rdV1(kt);
        tile(kf, v0, v1, qfB, accB0, accB1, accB2, false);
        tile(kf, v0, v1, qfA, accA0, accA1, accA2, false);
    }
    {   // kt == tA: A's diagonal; B regular (tA < tB)
        const s16x8 kf = rdK(tA);
        const s16x4 v0 = rdV0(tA), v1 = rdV1(tA);
        tile(kf, v0, v1, qfB, accB0, accB1, accB2, false);
        tile(kf, v0, v1, qfA, accA0, accA1, accA2, true);
    }
    for (int kt = tA + 1; kt < tB; ++kt) {
        const s16x8 kf = rdK(kt);
        const s16x4 v0 = rdV0(kt), v1 = rdV1(kt);
        tile(kf, v0, v1, qfB, accB0, accB1, accB2, false);
    }
    {   // kt == tB: B's diagonal
        const s16x8 kf = rdK(tB);
        const s16x4 v0 = rdV0(tB), v1 = rdV1(tB);
        tile(kf, v0, v1, qfB, accB0, accB1, accB2, true);
    }
    __builtin_amdgcn_s_setprio(0);

    auto store_o = [&](int jbase, const f32x4& o0, const f32x4& o1, float sum) {
        const float rinv = 1.0f / sum;    // sum identical across lanes' regs for this j=l15
        uint2 w0, w1;
        w0.x = pk2(o0[0] * rinv, o0[1] * rinv);
        w0.y = pk2(o0[2] * rinv, o0[3] * rinv);
        w1.x = pk2(o1[0] * rinv, o1[1] * rinv);
        w1.y = pk2(o1[2] * rinv, o1[3] * rinv);
        u16* orow = o_ws + obase + (size_t)(jbase + l15) * 512;
        *reinterpret_cast<uint2*>(orow + g * 4) = w0;
        *reinterpret_cast<uint2*>(orow + 16 + g * 4) = w1;
    };
    store_o(tA * 16, accA0, accA1, accA2[0]);
    store_o(tB * 16, accB0, accB1, accB2[0]);
}

// ---------------- output projection + residual ----------------
// Block decode keeps each 64-row tile on the XCD whose fused_attn blocks
// produced those o rows (producer XCD = i>>5 = (b'>>7)).
__global__ __launch_bounds__(256) void outproj(const u16* __restrict__ o_ws,
                                               const u16* __restrict__ wo_t,
                                               const float* __restrict__ pair,
                                               const float* __restrict__ bo,
                                               float* __restrict__ out) {
    __shared__ u16 As[64 * 72];
    __shared__ u16 Bs[128 * 72];
    const int tid = threadIdx.x;
    const int d = blockIdx.x;
    const int bb = ((d & 7) << 7) | (d >> 3);    // (bb>>7) == d&7 == XCD
    const int m0 = bb * 64;
    const int wave = tid >> 6, lane = tid & 63;
    const int g = lane >> 4, l15 = lane & 15;

    f32x4 acc[8];
    for (int c = 0; c < 8; ++c) acc[c] = f32x4{0.f, 0.f, 0.f, 0.f};

    for (int kt = 0; kt < 8; ++kt) {
        __syncthreads();
        for (int it = 0; it < 2; ++it) {
            int L = tid + it * 256;
            int row = L >> 3, seg = L & 7;
            *reinterpret_cast<s16x8*>(&As[row * 72 + seg * 8]) =
                *reinterpret_cast<const s16x8*>(o_ws + (size_t)(m0 + row) * 512 + kt * 64 + seg * 8);
        }
        for (int it = 0; it < 4; ++it) {
            int L = tid + it * 256;
            int n = L >> 3, seg = L & 7;
            *reinterpret_cast<s16x8*>(&Bs[n * 72 + seg * 8]) =
                *reinterpret_cast<const s16x8*>(wo_t + (size_t)n * 512 + kt * 64 + seg * 8);
        }
        __syncthreads();
        for (int kk = 0; kk < 2; ++kk) {
            const s16x8 a = *reinterpret_cast<s16x8*>(&As[(wave * 16 + l15) * 72 + kk * 32 + g * 8]);
            for (int c = 0; c < 8; ++c) {
                const s16x8 b = *reinterpret_cast<s16x8*>(&Bs[(c * 16 + l15) * 72 + kk * 32 + g * 8]);
                acc[c] = __builtin_amdgcn_mfma_f32_16x16x32_bf16(a, b, acc[c], 0, 0, 0);
            }
        }
    }

    for (int c = 0; c < 8; ++c) {
        const int n = c * 16 + l15;
        const float bias = bo[n];
        for (int r = 0; r < 4; ++r) {
            const size_t row = m0 + wave * 16 + g * 4 + r;
            out[row * 128 + n] = acc[c][r] + bias + pair[row * 128 + n];
        }
    }
}

extern "C" void kernel_launch(void* const* d_in, const int* in_sizes, int n_in,
                              void* d_out, int out_size, void* d_ws, size_t ws_size,
                              hipStream_t stream) {
    const float* pair = (const float*)d_in[0];
    const float* Wq = (const float*)d_in[1];
    const float* bq = (const float*)d_in[2];
    const float* Wk = (const float*)d_in[3];
    const float* bk = (const float*)d_in[4];
    const float* Wv = (const float*)d_in[5];
    const float* bv = (const float*)d_in[6];
    const float* Wo = (const float*)d_in[7];
    const float* bo = (const float*)d_in[8];
    float* out = (float*)d_out;

    char* ws = (char*)d_ws;
    u16* o_ws  = (u16*)(ws);                       // 64 MiB
    u16* wq_t  = (u16*)(ws + 67108864);            // 128 KiB each
    u16* wk_t  = wq_t + 65536;
    u16* wv_t  = wk_t + 65536;
    u16* wo_t  = wv_t + 65536;
    u16* pairb = (u16*)(ws + 67108864 + 1048576);  // 16 MiB

    prep_all<<<5120, 256, 0, stream>>>(Wq, Wk, Wv, Wo, pair,
                                       wq_t, wk_t, wv_t, wo_t, pairb);
    fused_attn<<<4096, 512, 0, stream>>>(pairb, wq_t, wk_t, wv_t, bq, bk, bv, o_ws);
    outproj<<<1024, 256, 0, stream>>>(o_ws, wo_t, pair, bo, out);
}